// Round 8
// baseline (165.122 us; speedup 1.0000x reference)
//
#include <hip/hip_runtime.h>
#include <math.h>

#define BB 2
#define MM 4096
#define NN 8192
#define CC 512
#define NC 20
#define OUTD 512
#define H1 128
#define H2 256
#define CIN 532      // C + NC
#define KNN 3
#define SPLIT 32
#define CHUNK (MM / SPLIT)   // 128
#define CLEN (CHUNK / 4)     // 32 points per chain

// up_kernel MFMA geometry
#define RR 32        // rows per block
#define HS 264       // hidden row stride in bf16
#define KT2 8        // k-tiles layer2 (K=256)
#define KT1 17       // k-tiles of packed W1 (K=544; kb 0..15 feat, kb 16 = P block)

// sem geometry (16 rows per block)
#define RO 16
#define FS 520       // sfeat stride (bf16)
#define HS2 136      // shid stride (bf16)
#define TS 512       // T row: [H(256) | G(256)] bf16
#define SKT1 16      // K=512
#define SKT2 4       // K=128

#define NPREP 544                     // 139264 / 256
#define NKNNB (BB * NN / 256 * SPLIT) // 2048 knn blocks

typedef __attribute__((ext_vector_type(8))) short s8;
typedef __attribute__((ext_vector_type(4))) float f4;

__device__ inline unsigned short f2bf(float x) {
    unsigned u = __float_as_uint(x);
    unsigned r = (u + 0x7FFFu + ((u >> 16) & 1u)) >> 16;
    return (unsigned short)r;
}
__device__ inline float bf2fs(short u) {
    return __uint_as_float(((unsigned)(unsigned short)u) << 16);
}

// ---------------- K1: weight packing (blocks < NPREP) + kNN partials ----------------
__global__ __launch_bounds__(256) void pk_kernel(
    const float* __restrict__ wu1, const float* __restrict__ wu2,
    const float* __restrict__ ws1, const float* __restrict__ ws2,
    unsigned short* __restrict__ w1p, unsigned short* __restrict__ w2p,
    unsigned short* __restrict__ ws1p, unsigned short* __restrict__ ws2p,
    const float* __restrict__ srcp, const float* __restrict__ tgtp,
    float* __restrict__ pd2, unsigned short* __restrict__ pidx)
{
    __shared__ float4 pts[CHUNK];      // 2 KB
    const int tid = threadIdx.x;
    const int bx = blockIdx.x;

    if (bx < NPREP) {
        int i = bx * 256 + tid;
        if (i < KT1 * H2 * 32) {            // upsample L1 (feat rows 0..511, P rows 512..531)
            int kk = i & 31, n = (i >> 5) & 255, kb = i >> 13;
            int k = kb * 32 + kk;
            w1p[i] = f2bf((k < CIN) ? wu1[(size_t)k * H2 + n] : 0.0f);
        }
        if (i < KT2 * OUTD * 32) {          // upsample L2
            int kk = i & 31, n = (i >> 5) & 511, kb = i >> 14;
            int k = kb * 32 + kk;
            w2p[i] = f2bf(wu2[(size_t)k * OUTD + n]);
        }
        if (i < SKT1 * H1 * 32) {           // semantic L1
            int kk = i & 31, n = (i >> 5) & 127, kb = i >> 12;
            int k = kb * 32 + kk;
            ws1p[i] = f2bf(ws1[(size_t)k * H1 + n]);
        }
        if (i < SKT2 * 32 * 32) {           // semantic L2 (N padded 20->32)
            int kk = i & 31, n = (i >> 5) & 31, kb = i >> 10;
            int k = kb * 32 + kk;
            ws2p[i] = f2bf((n < NC) ? ws2[(size_t)k * NC + n] : 0.0f);
        }
        return;
    }

    // ---- kNN partial: one 128-pt chunk vs 256 targets ----
    const int bx2 = bx - NPREP;        // 0..2047
    const int g = bx2 & 63;            // target group (uniform)
    const int chunk = bx2 >> 6;        // 0..31
    const int t = g * 256 + tid;
    const int bu = g >> 5;             // uniform batch
    const int mbase = chunk * CHUNK;

    if (tid < CHUNK) {
        const float* spg = srcp + ((size_t)bu * MM + mbase) * 3;
        float x = spg[tid * 3 + 0];
        float y = spg[tid * 3 + 1];
        float z = spg[tid * 3 + 2];
        pts[tid] = make_float4(x, y, z, x * x + y * y + z * z);
    }
    __syncthreads();

    const float tx = tgtp[(size_t)t * 3 + 0];
    const float ty = tgtp[(size_t)t * 3 + 1];
    const float tz = tgtp[(size_t)t * 3 + 2];
    const float m2x = -2.0f * tx, m2y = -2.0f * ty, m2z = -2.0f * tz;

    float b0[4], b1[4], b2[4];
    int i0[4], i1[4], i2[4];
#pragma unroll
    for (int k = 0; k < 4; ++k) {
        b0[k] = b1[k] = b2[k] = 1e30f;
        i0[k] = i1[k] = i2[k] = 0;
    }

#pragma unroll 4
    for (int m = 0; m < CLEN; ++m) {
#pragma unroll
        for (int k = 0; k < 4; ++k) {
            float4 p = pts[k * CLEN + m];          // broadcast ds_read (conflict-free)
            float d = fmaf(m2x, p.x, fmaf(m2y, p.y, fmaf(m2z, p.z, p.w)));
            int mi = mbase + k * CLEN + m;          // wave-uniform
            bool l2 = d < b2[k], l1 = d < b1[k], l0 = d < b0[k];
            b2[k] = l1 ? b1[k] : (l2 ? d : b2[k]); i2[k] = l1 ? i1[k] : (l2 ? mi : i2[k]);
            b1[k] = l0 ? b0[k] : (l1 ? d : b1[k]); i1[k] = l0 ? i0[k] : (l1 ? mi : i1[k]);
            b0[k] = l0 ? d : b0[k];                i0[k] = l0 ? mi : i0[k];
        }
    }
    // merge chains 1..3 into chain 0 (ascending index ranges -> '<' is stable)
#pragma unroll
    for (int k = 1; k < 4; ++k) {
#pragma unroll
        for (int j = 0; j < 3; ++j) {
            float d = (j == 0) ? b0[k] : (j == 1) ? b1[k] : b2[k];
            int   i = (j == 0) ? i0[k] : (j == 1) ? i1[k] : i2[k];
            bool e2 = d < b2[0], e1 = d < b1[0], e0 = d < b0[0];
            b2[0] = e1 ? b1[0] : (e2 ? d : b2[0]); i2[0] = e1 ? i1[0] : (e2 ? i : i2[0]);
            b1[0] = e0 ? b0[0] : (e1 ? d : b1[0]); i1[0] = e0 ? i0[0] : (e1 ? i : i1[0]);
            b0[0] = e0 ? d : b0[0];                i0[0] = e0 ? i : i0[0];
        }
    }
    size_t o = ((size_t)t * SPLIT + chunk) * KNN;
    pd2[o + 0] = b0[0]; pd2[o + 1] = b1[0]; pd2[o + 2] = b2[0];
    pidx[o + 0] = (unsigned short)i0[0];
    pidx[o + 1] = (unsigned short)i1[0];
    pidx[o + 2] = (unsigned short)i2[0];
}

// ---------------- K2: semantic MLP + H/G source tables (bf16 MFMA) ----------------
// Tst overlays sfeat (dead after the K-loop) -> 23.6 KB LDS, 6 blocks/CU.
__global__ __launch_bounds__(256) void sem_kernel(
    const float* __restrict__ feat,
    const unsigned short* __restrict__ ws1p, const unsigned short* __restrict__ ws2p,
    const unsigned short* __restrict__ w1p,
    const float* __restrict__ b1s, const float* __restrict__ b2s,
    float* __restrict__ logits_out, unsigned short* __restrict__ T)
{
    __shared__ __align__(16) char smem[24128];
    unsigned short* sfeat = (unsigned short*)smem;            // 16640 B
    unsigned short* Tst   = (unsigned short*)smem;            // 16384 B (ALIAS of sfeat)
    unsigned short* shid  = (unsigned short*)(smem + 16640);  // 4352 B
    float*          slg   = (float*)(smem + 20992);           // 2112 B [r*33+c]
    unsigned short* pP    = (unsigned short*)(smem + 23104);  // 1024 B
    const int tid = threadIdx.x;
    const int row0 = blockIdx.x * RO;
    const int lane = tid & 63;
    const int wv = tid >> 6;
    const int l15 = lane & 15;
    const int quad = lane >> 4;

    // stage feat rows as bf16 (16 threads/row)
    {
        const int r = tid >> 4, p = tid & 15;
        const float4* fr = (const float4*)(feat + (size_t)(row0 + r) * CC);
#pragma unroll
        for (int j = 0; j < 8; ++j) {
            int c4 = j * 16 + p;
            float4 a = fr[c4];
            ushort4 s;
            s.x = f2bf(a.x); s.y = f2bf(a.y); s.z = f2bf(a.z); s.w = f2bf(a.w);
            *(ushort4*)&sfeat[r * FS + c4 * 4] = s;
        }
    }
    __syncthreads();

    // combined L1: sem (128 cols) + H (256 cols), K=512
    f4 asem[2], ah[4];
    {
#pragma unroll
        for (int c = 0; c < 2; ++c) asem[c] = (f4){0.f, 0.f, 0.f, 0.f};
#pragma unroll
        for (int c = 0; c < 4; ++c) ah[c] = (f4){0.f, 0.f, 0.f, 0.f};
        for (int kb = 0; kb < SKT1; ++kb) {
            s8 a = *(const s8*)&sfeat[l15 * FS + kb * 32 + quad * 8];
#pragma unroll
            for (int c = 0; c < 2; ++c) {
                s8 b = *(const s8*)&ws1p[((size_t)(kb * H1 + wv * 32 + c * 16 + l15)) * 32 + quad * 8];
                asem[c] = __builtin_amdgcn_mfma_f32_16x16x32_bf16(a, b, asem[c], 0, 0, 0);
            }
#pragma unroll
            for (int c = 0; c < 4; ++c) {
                s8 b = *(const s8*)&w1p[((size_t)(kb * H2 + wv * 64 + c * 16 + l15)) * 32 + quad * 8];
                ah[c] = __builtin_amdgcn_mfma_f32_16x16x32_bf16(a, b, ah[c], 0, 0, 0);
            }
        }
    }
    __syncthreads();   // all sfeat reads complete -> safe to overwrite via Tst alias
    {
#pragma unroll
        for (int c = 0; c < 2; ++c) {
            int col = wv * 32 + c * 16 + l15;
            float bias = b1s[col];
#pragma unroll
            for (int i = 0; i < 4; ++i) {
                int rr = quad * 4 + i;
                shid[rr * HS2 + col] = f2bf(fmaxf(asem[c][i] + bias, 0.0f));
            }
        }
#pragma unroll
        for (int c = 0; c < 4; ++c) {
            int col = wv * 64 + c * 16 + l15;
#pragma unroll
            for (int i = 0; i < 4; ++i) {
                int rr = quad * 4 + i;
                Tst[rr * TS + col] = f2bf(ah[c][i]);   // H (bias added in up_kernel)
            }
        }
    }
    __syncthreads();

    // sem L2: [16 x 128] @ [128 x 32(20)] (waves 0,1)
    if (wv < 2) {
        f4 acc = (f4){0.f, 0.f, 0.f, 0.f};
        for (int kb = 0; kb < SKT2; ++kb) {
            s8 a = *(const s8*)&shid[l15 * HS2 + kb * 32 + quad * 8];
            s8 b = *(const s8*)&ws2p[((size_t)(kb * 32 + wv * 16 + l15)) * 32 + quad * 8];
            acc = __builtin_amdgcn_mfma_f32_16x16x32_bf16(a, b, acc, 0, 0, 0);
        }
        int col = wv * 16 + l15;
        float bias = (col < NC) ? b2s[col] : 0.0f;
#pragma unroll
        for (int i = 0; i < 4; ++i) {
            int rr = quad * 4 + i;
            float v = acc[i] + bias;
            slg[rr * 33 + col] = v;
            if (col < NC)
                logits_out[(size_t)(row0 + rr) * NC + col] = v;
        }
    }
    __syncthreads();

    // softmax -> pP (bf16, padded to 32)
    if (tid < RO) {
        int r = tid;
        float mx = -1e30f;
        for (int nc = 0; nc < NC; ++nc) mx = fmaxf(mx, slg[r * 33 + nc]);
        float s = 0.0f;
        float e[NC];
#pragma unroll
        for (int nc = 0; nc < NC; ++nc) { e[nc] = __expf(slg[r * 33 + nc] - mx); s += e[nc]; }
        float inv = 1.0f / s;
#pragma unroll
        for (int nc = 0; nc < 32; ++nc)
            pP[r * 32 + nc] = (nc < NC) ? f2bf(e[nc] * inv) : 0;
    }
    __syncthreads();

    // G = P @ W1b (K=32, kb=16 of packed W1)
    {
        s8 a = *(const s8*)&pP[l15 * 32 + quad * 8];
#pragma unroll
        for (int c = 0; c < 4; ++c) {
            s8 b = *(const s8*)&w1p[((size_t)(16 * H2 + wv * 64 + c * 16 + l15)) * 32 + quad * 8];
            f4 acc = (f4){0.f, 0.f, 0.f, 0.f};
            acc = __builtin_amdgcn_mfma_f32_16x16x32_bf16(a, b, acc, 0, 0, 0);
            int col = wv * 64 + c * 16 + l15;
#pragma unroll
            for (int i = 0; i < 4; ++i) {
                int rr = quad * 4 + i;
                Tst[rr * TS + 256 + col] = f2bf(acc[i]);
            }
        }
    }
    __syncthreads();

    // coalesced store of T rows
    {
#pragma unroll
        for (int v = 0; v < 4; ++v) {
            int e = (tid + v * 256) * 8;            // 0..8191, step 8
            int r = e >> 9, c = e & (TS - 1);
            s8 d = *(const s8*)&Tst[e];
            *(s8*)&T[((size_t)(row0 + r)) * TS + c] = d;
        }
    }
}

// ---------------- K3: merge + T-gather + L2 MFMA ----------------
__global__ __launch_bounds__(256) void up_kernel(
    const unsigned short* __restrict__ T,
    const float* __restrict__ pd2, const unsigned short* __restrict__ pidx,
    const float* __restrict__ tgtp,
    const unsigned short* __restrict__ w2p,
    const float* __restrict__ b1g, const float* __restrict__ b2g,
    float* __restrict__ out)
{
    __shared__ unsigned short hid[RR * HS];
    __shared__ float sg[RR][3];
    __shared__ int   sj[RR][3];
    __shared__ float pb[RR][4][3];
    __shared__ int   pi[RR][4][3];
    const int tid = threadIdx.x;
    const int row0 = blockIdx.x * RR;
    const int lane = tid & 63;
    const int wv = tid >> 6;
    const int l15 = lane & 15;
    const int quad = lane >> 4;

    // stage A1: 4 threads/row, each merges 8 chunks (24 partial entries)
    if (tid < RR * 4) {
        const int r = tid >> 2, p = tid & 3;
        int row = row0 + r;
        float b0 = 1e30f, b1 = 1e30f, b2 = 1e30f;
        int i0 = 0, i1 = 0, i2 = 0;
        size_t base = (size_t)row * SPLIT * KNN + (size_t)p * 8 * KNN;
#pragma unroll
        for (int j = 0; j < 8 * KNN; ++j) {
            float d = pd2[base + j];
            int m = pidx[base + j];
            bool l2 = d < b2, l1 = d < b1, l0 = d < b0;
            b2 = l1 ? b1 : (l2 ? d : b2); i2 = l1 ? i1 : (l2 ? m : i2);
            b1 = l0 ? b0 : (l1 ? d : b1); i1 = l0 ? i0 : (l1 ? m : i1);
            b0 = l0 ? d : b0;             i0 = l0 ? m : i0;
        }
        pb[r][p][0] = b0; pb[r][p][1] = b1; pb[r][p][2] = b2;
        pi[r][p][0] = i0; pi[r][p][1] = i1; pi[r][p][2] = i2;
    }
    __syncthreads();

    // stage A2: final merge of 12 entries + softmax(-d) weights
    if (tid < RR) {
        int row = row0 + tid;
        float b0 = 1e30f, b1 = 1e30f, b2 = 1e30f;
        int i0 = 0, i1 = 0, i2 = 0;
#pragma unroll
        for (int p = 0; p < 4; ++p)
#pragma unroll
            for (int j = 0; j < 3; ++j) {
                float d = pb[tid][p][j];
                int m = pi[tid][p][j];
                bool l2 = d < b2, l1 = d < b1, l0 = d < b0;
                b2 = l1 ? b1 : (l2 ? d : b2); i2 = l1 ? i1 : (l2 ? m : i2);
                b1 = l0 ? b0 : (l1 ? d : b1); i1 = l0 ? i0 : (l1 ? m : i1);
                b0 = l0 ? d : b0;             i0 = l0 ? m : i0;
            }
        float tx = tgtp[(size_t)row * 3 + 0];
        float ty = tgtp[(size_t)row * 3 + 1];
        float tz = tgtp[(size_t)row * 3 + 2];
        float t2 = tx * tx + ty * ty + tz * tz;
        float d0 = sqrtf(fmaxf(b0 + t2, 0.0f));
        float d1 = sqrtf(fmaxf(b1 + t2, 0.0f));
        float d2v = sqrtf(fmaxf(b2 + t2, 0.0f));
        float e1 = __expf(d0 - d1);
        float e2 = __expf(d0 - d2v);
        float inv = 1.0f / (1.0f + e1 + e2);
        sg[tid][0] = inv; sg[tid][1] = e1 * inv; sg[tid][2] = e2 * inv;
        sj[tid][0] = i0; sj[tid][1] = i1; sj[tid][2] = i2;
    }
    __syncthreads();

    // stage B: gather T rows, pre = sum g_k*H[j_k] + (1/3) sum G[j_k]; relu -> hid
    {
        const int r = tid >> 3, p = tid & 7, c0 = p * 32;
        int row = row0 + r;
        size_t bofs = (size_t)(row >> 13) * MM;
        float pre[32];
#pragma unroll
        for (int cc = 0; cc < 32; ++cc) pre[cc] = 0.0f;
#pragma unroll
        for (int k = 0; k < 3; ++k) {
            const unsigned short* Tr = T + (bofs + (size_t)sj[r][k]) * TS;
            float gk = sg[r][k];
#pragma unroll
            for (int v = 0; v < 4; ++v) {
                s8 h = *(const s8*)&Tr[c0 + v * 8];
                s8 g = *(const s8*)&Tr[256 + c0 + v * 8];
#pragma unroll
                for (int e = 0; e < 8; ++e) {
                    pre[v * 8 + e] = fmaf(gk, bf2fs(h[e]), pre[v * 8 + e]);
                    pre[v * 8 + e] = fmaf(1.0f / 3.0f, bf2fs(g[e]), pre[v * 8 + e]);
                }
            }
        }
#pragma unroll
        for (int cc = 0; cc < 32; ++cc) {
            int c = c0 + cc;
            hid[r * HS + c] = f2bf(fmaxf(pre[cc] + b1g[c], 0.0f));
        }
    }
    __syncthreads();

    // stage C: L2 MFMA [32 x 256] @ [256 x 512] + bias -> out
    {
        const int m0 = wv * 128;
        f4 acc2[2][8];
#pragma unroll
        for (int rt = 0; rt < 2; ++rt)
#pragma unroll
            for (int c = 0; c < 8; ++c) acc2[rt][c] = (f4){0.f, 0.f, 0.f, 0.f};
        for (int kb = 0; kb < KT2; ++kb) {
            s8 a0 = *(const s8*)&hid[l15 * HS + kb * 32 + quad * 8];
            s8 a1 = *(const s8*)&hid[(l15 + 16) * HS + kb * 32 + quad * 8];
            s8 bfr[8];
#pragma unroll
            for (int c = 0; c < 8; ++c)
                bfr[c] = *(const s8*)&w2p[((size_t)(kb * OUTD + m0 + c * 16 + l15)) * 32 + quad * 8];
#pragma unroll
            for (int c = 0; c < 8; ++c) {
                acc2[0][c] = __builtin_amdgcn_mfma_f32_16x16x32_bf16(a0, bfr[c], acc2[0][c], 0, 0, 0);
                acc2[1][c] = __builtin_amdgcn_mfma_f32_16x16x32_bf16(a1, bfr[c], acc2[1][c], 0, 0, 0);
            }
        }
#pragma unroll
        for (int c = 0; c < 8; ++c) {
            int ccol = m0 + c * 16 + l15;
            float bias = b2g[ccol];
#pragma unroll
            for (int rt = 0; rt < 2; ++rt)
#pragma unroll
                for (int i = 0; i < 4; ++i) {
                    int rr = rt * 16 + quad * 4 + i;
                    out[(size_t)(row0 + rr) * OUTD + ccol] = acc2[rt][c][i] + bias;
                }
        }
    }
}

extern "C" void kernel_launch(void* const* d_in, const int* in_sizes, int n_in,
                              void* d_out, int out_size, void* d_ws, size_t ws_size,
                              hipStream_t stream) {
    (void)in_sizes; (void)n_in; (void)out_size; (void)ws_size;
    const float* src_points   = (const float*)d_in[0];
    const float* tgt_points   = (const float*)d_in[1];
    const float* src_features = (const float*)d_in[2];
    const float* w_sem1 = (const float*)d_in[3];
    const float* b_sem1 = (const float*)d_in[4];
    const float* w_sem2 = (const float*)d_in[5];
    const float* b_sem2 = (const float*)d_in[6];
    const float* w_up1  = (const float*)d_in[7];
    const float* b_up1  = (const float*)d_in[8];
    const float* w_up2  = (const float*)d_in[9];
    const float* b_up2  = (const float*)d_in[10];

    float* out    = (float*)d_out;
    float* ups    = out;
    float* logits = out + (size_t)BB * NN * OUTD;

    // workspace layout (~18.5 MB of 256 MiB)
    char* w = (char*)d_ws;
    unsigned short* T = (unsigned short*)w;    w += (size_t)BB * MM * TS * 2;          // 8388608
    float* pd2  = (float*)w;                   w += (size_t)BB * NN * SPLIT * KNN * 4; // 6291456
    unsigned short* pidx = (unsigned short*)w; w += (size_t)BB * NN * SPLIT * KNN * 2; // 3145728
    unsigned short* w1p  = (unsigned short*)w; w += (size_t)KT1 * H2 * 32 * 2;         // 278528
    unsigned short* w2p  = (unsigned short*)w; w += (size_t)KT2 * OUTD * 32 * 2;       // 262144
    unsigned short* ws1p = (unsigned short*)w; w += (size_t)SKT1 * H1 * 32 * 2;        // 131072
    unsigned short* ws2p = (unsigned short*)w; w += (size_t)SKT2 * 32 * 32 * 2;        // 8192

    pk_kernel<<<dim3(NPREP + NKNNB), dim3(256), 0, stream>>>(
        w_up1, w_up2, w_sem1, w_sem2, w1p, w2p, ws1p, ws2p,
        src_points, tgt_points, pd2, pidx);
    sem_kernel<<<dim3(BB * MM / RO), dim3(256), 0, stream>>>(
        src_features, ws1p, ws2p, w1p, b_sem1, b_sem2, logits, T);
    up_kernel<<<dim3(BB * NN / RR), dim3(256), 0, stream>>>(
        T, pd2, pidx, tgt_points, w2p, b_up1, b_up2, ups);
}

// Round 9
// 159.009 us; speedup vs baseline: 1.0384x; 1.0384x over previous
//
#include <hip/hip_runtime.h>
#include <math.h>

#define BB 2
#define MM 4096
#define NN 8192
#define CC 512
#define NC 20
#define OUTD 512
#define H1 128
#define H2 256
#define CIN 532      // C + NC
#define KNN 3
#define SPLIT 32
#define CHUNK (MM / SPLIT)   // 128
#define CLEN (CHUNK / 4)     // 32 points per chain

// up_kernel MFMA geometry
#define RR 32        // rows per block
#define HS 264       // hidden row stride in bf16
#define KT2 8        // k-tiles layer2 (K=256)
#define KT1 17       // k-tiles of packed W1 (K=544; kb 0..15 feat, kb 16 = P block)

// sem geometry (16 rows per block)
#define RO 16
#define FS 520       // sfeat stride (bf16)
#define HS2 136      // shid stride (bf16)
#define TS 512       // T row: [H(256) | G(256)] bf16
#define SKT1 16      // K=512
#define SKT2 4       // K=128

#define NPREP 544                     // 139264 / 256
#define NKNNB (BB * NN / 256 * SPLIT) // 2048 knn blocks
#define NSEMB (BB * MM / RO)          // 512 sem blocks

typedef __attribute__((ext_vector_type(8))) short s8;
typedef __attribute__((ext_vector_type(4))) float f4;

__device__ inline unsigned short f2bf(float x) {
    unsigned u = __float_as_uint(x);
    unsigned r = (u + 0x7FFFu + ((u >> 16) & 1u)) >> 16;
    return (unsigned short)r;
}
__device__ inline float bf2fs(short u) {
    return __uint_as_float(((unsigned)(unsigned short)u) << 16);
}

// ---------------- K0: pack all bf16 weights (must finish before sem blocks run) ----------------
__global__ __launch_bounds__(256) void prep_kernel(
    const float* __restrict__ wu1, const float* __restrict__ wu2,
    const float* __restrict__ ws1, const float* __restrict__ ws2,
    unsigned short* __restrict__ w1p, unsigned short* __restrict__ w2p,
    unsigned short* __restrict__ ws1p, unsigned short* __restrict__ ws2p)
{
    int i = blockIdx.x * 256 + threadIdx.x;
    if (i < KT1 * H2 * 32) {            // upsample L1 (feat rows 0..511, P rows 512..531)
        int kk = i & 31, n = (i >> 5) & 255, kb = i >> 13;
        int k = kb * 32 + kk;
        w1p[i] = f2bf((k < CIN) ? wu1[(size_t)k * H2 + n] : 0.0f);
    }
    if (i < KT2 * OUTD * 32) {          // upsample L2
        int kk = i & 31, n = (i >> 5) & 511, kb = i >> 14;
        int k = kb * 32 + kk;
        w2p[i] = f2bf(wu2[(size_t)k * OUTD + n]);
    }
    if (i < SKT1 * H1 * 32) {           // semantic L1
        int kk = i & 31, n = (i >> 5) & 127, kb = i >> 12;
        int k = kb * 32 + kk;
        ws1p[i] = f2bf(ws1[(size_t)k * H1 + n]);
    }
    if (i < SKT2 * 32 * 32) {           // semantic L2 (N padded 20->32)
        int kk = i & 31, n = (i >> 5) & 31, kb = i >> 10;
        int k = kb * 32 + kk;
        ws2p[i] = f2bf((n < NC) ? ws2[(size_t)k * NC + n] : 0.0f);
    }
}

// ---------------- K1: fused kNN partials (blocks < NKNNB) + sem MLP / T tables ----------------
// 23.6 KB static LDS -> 6 blocks/CU; knn's VALU waves co-schedule with sem's MFMA/mem waves.
__global__ __launch_bounds__(256) void fused_kernel(
    const float* __restrict__ srcp, const float* __restrict__ tgtp,
    float* __restrict__ pd2, unsigned short* __restrict__ pidx,
    const float* __restrict__ feat,
    const unsigned short* __restrict__ ws1p, const unsigned short* __restrict__ ws2p,
    const unsigned short* __restrict__ w1p,
    const float* __restrict__ b1s, const float* __restrict__ b2s,
    float* __restrict__ logits_out, unsigned short* __restrict__ T)
{
    __shared__ __align__(16) char smem[24128];
    const int tid = threadIdx.x;
    const int bx = blockIdx.x;

    if (bx < NKNNB) {
        // ================= kNN partial block: one 128-pt chunk vs 256 targets =================
        float4* pts = (float4*)smem;       // 2 KB
        const int g = bx & 63;             // target group (uniform)
        const int chunk = bx >> 6;         // 0..31
        const int t = g * 256 + tid;
        const int bu = g >> 5;             // uniform batch
        const int mbase = chunk * CHUNK;

        if (tid < CHUNK) {
            const float* spg = srcp + ((size_t)bu * MM + mbase) * 3;
            float x = spg[tid * 3 + 0];
            float y = spg[tid * 3 + 1];
            float z = spg[tid * 3 + 2];
            pts[tid] = make_float4(x, y, z, x * x + y * y + z * z);
        }
        __syncthreads();

        const float tx = tgtp[(size_t)t * 3 + 0];
        const float ty = tgtp[(size_t)t * 3 + 1];
        const float tz = tgtp[(size_t)t * 3 + 2];
        const float m2x = -2.0f * tx, m2y = -2.0f * ty, m2z = -2.0f * tz;

        float b0[4], b1[4], b2[4];
        int i0[4], i1[4], i2[4];
#pragma unroll
        for (int k = 0; k < 4; ++k) {
            b0[k] = b1[k] = b2[k] = 1e30f;
            i0[k] = i1[k] = i2[k] = 0;
        }

#pragma unroll 4
        for (int m = 0; m < CLEN; ++m) {
#pragma unroll
            for (int k = 0; k < 4; ++k) {
                float4 p = pts[k * CLEN + m];          // broadcast ds_read (conflict-free)
                float d = fmaf(m2x, p.x, fmaf(m2y, p.y, fmaf(m2z, p.z, p.w)));
                int mi = mbase + k * CLEN + m;          // wave-uniform
                bool l2 = d < b2[k], l1 = d < b1[k], l0 = d < b0[k];
                b2[k] = l1 ? b1[k] : (l2 ? d : b2[k]); i2[k] = l1 ? i1[k] : (l2 ? mi : i2[k]);
                b1[k] = l0 ? b0[k] : (l1 ? d : b1[k]); i1[k] = l0 ? i0[k] : (l1 ? mi : i1[k]);
                b0[k] = l0 ? d : b0[k];                i0[k] = l0 ? mi : i0[k];
            }
        }
        // merge chains 1..3 into chain 0 (ascending index ranges -> '<' is stable)
#pragma unroll
        for (int k = 1; k < 4; ++k) {
#pragma unroll
            for (int j = 0; j < 3; ++j) {
                float d = (j == 0) ? b0[k] : (j == 1) ? b1[k] : b2[k];
                int   i = (j == 0) ? i0[k] : (j == 1) ? i1[k] : i2[k];
                bool e2 = d < b2[0], e1 = d < b1[0], e0 = d < b0[0];
                b2[0] = e1 ? b1[0] : (e2 ? d : b2[0]); i2[0] = e1 ? i1[0] : (e2 ? i : i2[0]);
                b1[0] = e0 ? b0[0] : (e1 ? d : b1[0]); i1[0] = e0 ? i0[0] : (e1 ? i : i1[0]);
                b0[0] = e0 ? d : b0[0];                i0[0] = e0 ? i : i0[0];
            }
        }
        size_t o = ((size_t)t * SPLIT + chunk) * KNN;
        pd2[o + 0] = b0[0]; pd2[o + 1] = b1[0]; pd2[o + 2] = b2[0];
        pidx[o + 0] = (unsigned short)i0[0];
        pidx[o + 1] = (unsigned short)i1[0];
        pidx[o + 2] = (unsigned short)i2[0];
        return;
    }

    // ================= semantic / T-table block =================
    unsigned short* sfeat = (unsigned short*)smem;            // 16640 B
    unsigned short* Tst   = (unsigned short*)smem;            // 16384 B (ALIAS of sfeat)
    unsigned short* shid  = (unsigned short*)(smem + 16640);  // 4352 B
    float*          slg   = (float*)(smem + 20992);           // 2112 B [r*33+c]
    unsigned short* pP    = (unsigned short*)(smem + 23104);  // 1024 B
    const int row0 = (bx - NKNNB) * RO;
    const int lane = tid & 63;
    const int wv = tid >> 6;
    const int l15 = lane & 15;
    const int quad = lane >> 4;

    // stage feat rows as bf16 (16 threads/row)
    {
        const int r = tid >> 4, p = tid & 15;
        const float4* fr = (const float4*)(feat + (size_t)(row0 + r) * CC);
#pragma unroll
        for (int j = 0; j < 8; ++j) {
            int c4 = j * 16 + p;
            float4 a = fr[c4];
            ushort4 s;
            s.x = f2bf(a.x); s.y = f2bf(a.y); s.z = f2bf(a.z); s.w = f2bf(a.w);
            *(ushort4*)&sfeat[r * FS + c4 * 4] = s;
        }
    }
    __syncthreads();

    // combined L1: sem (128 cols) + H (256 cols), K=512
    f4 asem[2], ah[4];
    {
#pragma unroll
        for (int c = 0; c < 2; ++c) asem[c] = (f4){0.f, 0.f, 0.f, 0.f};
#pragma unroll
        for (int c = 0; c < 4; ++c) ah[c] = (f4){0.f, 0.f, 0.f, 0.f};
        for (int kb = 0; kb < SKT1; ++kb) {
            s8 a = *(const s8*)&sfeat[l15 * FS + kb * 32 + quad * 8];
#pragma unroll
            for (int c = 0; c < 2; ++c) {
                s8 b = *(const s8*)&ws1p[((size_t)(kb * H1 + wv * 32 + c * 16 + l15)) * 32 + quad * 8];
                asem[c] = __builtin_amdgcn_mfma_f32_16x16x32_bf16(a, b, asem[c], 0, 0, 0);
            }
#pragma unroll
            for (int c = 0; c < 4; ++c) {
                s8 b = *(const s8*)&w1p[((size_t)(kb * H2 + wv * 64 + c * 16 + l15)) * 32 + quad * 8];
                ah[c] = __builtin_amdgcn_mfma_f32_16x16x32_bf16(a, b, ah[c], 0, 0, 0);
            }
        }
    }
    __syncthreads();   // all sfeat reads complete -> safe to overwrite via Tst alias
    {
#pragma unroll
        for (int c = 0; c < 2; ++c) {
            int col = wv * 32 + c * 16 + l15;
            float bias = b1s[col];
#pragma unroll
            for (int i = 0; i < 4; ++i) {
                int rr = quad * 4 + i;
                shid[rr * HS2 + col] = f2bf(fmaxf(asem[c][i] + bias, 0.0f));
            }
        }
#pragma unroll
        for (int c = 0; c < 4; ++c) {
            int col = wv * 64 + c * 16 + l15;
#pragma unroll
            for (int i = 0; i < 4; ++i) {
                int rr = quad * 4 + i;
                Tst[rr * TS + col] = f2bf(ah[c][i]);   // H (bias added in up_kernel)
            }
        }
    }
    __syncthreads();

    // sem L2: [16 x 128] @ [128 x 32(20)] (waves 0,1)
    if (wv < 2) {
        f4 acc = (f4){0.f, 0.f, 0.f, 0.f};
        for (int kb = 0; kb < SKT2; ++kb) {
            s8 a = *(const s8*)&shid[l15 * HS2 + kb * 32 + quad * 8];
            s8 b = *(const s8*)&ws2p[((size_t)(kb * 32 + wv * 16 + l15)) * 32 + quad * 8];
            acc = __builtin_amdgcn_mfma_f32_16x16x32_bf16(a, b, acc, 0, 0, 0);
        }
        int col = wv * 16 + l15;
        float bias = (col < NC) ? b2s[col] : 0.0f;
#pragma unroll
        for (int i = 0; i < 4; ++i) {
            int rr = quad * 4 + i;
            float v = acc[i] + bias;
            slg[rr * 33 + col] = v;
            if (col < NC)
                logits_out[(size_t)(row0 + rr) * NC + col] = v;
        }
    }
    __syncthreads();

    // softmax -> pP (bf16, padded to 32)
    if (tid < RO) {
        int r = tid;
        float mx = -1e30f;
        for (int nc = 0; nc < NC; ++nc) mx = fmaxf(mx, slg[r * 33 + nc]);
        float s = 0.0f;
        float e[NC];
#pragma unroll
        for (int nc = 0; nc < NC; ++nc) { e[nc] = __expf(slg[r * 33 + nc] - mx); s += e[nc]; }
        float inv = 1.0f / s;
#pragma unroll
        for (int nc = 0; nc < 32; ++nc)
            pP[r * 32 + nc] = (nc < NC) ? f2bf(e[nc] * inv) : 0;
    }
    __syncthreads();

    // G = P @ W1b (K=32, kb=16 of packed W1)
    {
        s8 a = *(const s8*)&pP[l15 * 32 + quad * 8];
#pragma unroll
        for (int c = 0; c < 4; ++c) {
            s8 b = *(const s8*)&w1p[((size_t)(16 * H2 + wv * 64 + c * 16 + l15)) * 32 + quad * 8];
            f4 acc = (f4){0.f, 0.f, 0.f, 0.f};
            acc = __builtin_amdgcn_mfma_f32_16x16x32_bf16(a, b, acc, 0, 0, 0);
            int col = wv * 64 + c * 16 + l15;
#pragma unroll
            for (int i = 0; i < 4; ++i) {
                int rr = quad * 4 + i;
                Tst[rr * TS + 256 + col] = f2bf(acc[i]);
            }
        }
    }
    __syncthreads();

    // coalesced store of T rows
    {
#pragma unroll
        for (int v = 0; v < 4; ++v) {
            int e = (tid + v * 256) * 8;            // 0..8191, step 8
            int r = e >> 9, c = e & (TS - 1);
            s8 d = *(const s8*)&Tst[e];
            *(s8*)&T[((size_t)(row0 + r)) * TS + c] = d;
        }
    }
}

// ---------------- K2: merge + T-gather + L2 MFMA ----------------
__global__ __launch_bounds__(256) void up_kernel(
    const unsigned short* __restrict__ T,
    const float* __restrict__ pd2, const unsigned short* __restrict__ pidx,
    const float* __restrict__ tgtp,
    const unsigned short* __restrict__ w2p,
    const float* __restrict__ b1g, const float* __restrict__ b2g,
    float* __restrict__ out)
{
    __shared__ unsigned short hid[RR * HS];
    __shared__ float sg[RR][3];
    __shared__ int   sj[RR][3];
    __shared__ float pb[RR][4][3];
    __shared__ int   pi[RR][4][3];
    const int tid = threadIdx.x;
    const int row0 = blockIdx.x * RR;
    const int lane = tid & 63;
    const int wv = tid >> 6;
    const int l15 = lane & 15;
    const int quad = lane >> 4;

    // stage A1: 4 threads/row, each merges 8 chunks (24 partial entries)
    if (tid < RR * 4) {
        const int r = tid >> 2, p = tid & 3;
        int row = row0 + r;
        float b0 = 1e30f, b1 = 1e30f, b2 = 1e30f;
        int i0 = 0, i1 = 0, i2 = 0;
        size_t base = (size_t)row * SPLIT * KNN + (size_t)p * 8 * KNN;
#pragma unroll
        for (int j = 0; j < 8 * KNN; ++j) {
            float d = pd2[base + j];
            int m = pidx[base + j];
            bool l2 = d < b2, l1 = d < b1, l0 = d < b0;
            b2 = l1 ? b1 : (l2 ? d : b2); i2 = l1 ? i1 : (l2 ? m : i2);
            b1 = l0 ? b0 : (l1 ? d : b1); i1 = l0 ? i0 : (l1 ? m : i1);
            b0 = l0 ? d : b0;             i0 = l0 ? m : i0;
        }
        pb[r][p][0] = b0; pb[r][p][1] = b1; pb[r][p][2] = b2;
        pi[r][p][0] = i0; pi[r][p][1] = i1; pi[r][p][2] = i2;
    }
    __syncthreads();

    // stage A2: final merge of 12 entries + softmax(-d) weights
    if (tid < RR) {
        int row = row0 + tid;
        float b0 = 1e30f, b1 = 1e30f, b2 = 1e30f;
        int i0 = 0, i1 = 0, i2 = 0;
#pragma unroll
        for (int p = 0; p < 4; ++p)
#pragma unroll
            for (int j = 0; j < 3; ++j) {
                float d = pb[tid][p][j];
                int m = pi[tid][p][j];
                bool l2 = d < b2, l1 = d < b1, l0 = d < b0;
                b2 = l1 ? b1 : (l2 ? d : b2); i2 = l1 ? i1 : (l2 ? m : i2);
                b1 = l0 ? b0 : (l1 ? d : b1); i1 = l0 ? i0 : (l1 ? m : i1);
                b0 = l0 ? d : b0;             i0 = l0 ? m : i0;
            }
        float tx = tgtp[(size_t)row * 3 + 0];
        float ty = tgtp[(size_t)row * 3 + 1];
        float tz = tgtp[(size_t)row * 3 + 2];
        float t2 = tx * tx + ty * ty + tz * tz;
        float d0 = sqrtf(fmaxf(b0 + t2, 0.0f));
        float d1 = sqrtf(fmaxf(b1 + t2, 0.0f));
        float d2v = sqrtf(fmaxf(b2 + t2, 0.0f));
        float e1 = __expf(d0 - d1);
        float e2 = __expf(d0 - d2v);
        float inv = 1.0f / (1.0f + e1 + e2);
        sg[tid][0] = inv; sg[tid][1] = e1 * inv; sg[tid][2] = e2 * inv;
        sj[tid][0] = i0; sj[tid][1] = i1; sj[tid][2] = i2;
    }
    __syncthreads();

    // stage B: gather T rows, pre = sum g_k*H[j_k] + (1/3) sum G[j_k]; relu -> hid
    {
        const int r = tid >> 3, p = tid & 7, c0 = p * 32;
        int row = row0 + r;
        size_t bofs = (size_t)(row >> 13) * MM;
        float pre[32];
#pragma unroll
        for (int cc = 0; cc < 32; ++cc) pre[cc] = 0.0f;
#pragma unroll
        for (int k = 0; k < 3; ++k) {
            const unsigned short* Tr = T + (bofs + (size_t)sj[r][k]) * TS;
            float gk = sg[r][k];
#pragma unroll
            for (int v = 0; v < 4; ++v) {
                s8 h = *(const s8*)&Tr[c0 + v * 8];
                s8 g = *(const s8*)&Tr[256 + c0 + v * 8];
#pragma unroll
                for (int e = 0; e < 8; ++e) {
                    pre[v * 8 + e] = fmaf(gk, bf2fs(h[e]), pre[v * 8 + e]);
                    pre[v * 8 + e] = fmaf(1.0f / 3.0f, bf2fs(g[e]), pre[v * 8 + e]);
                }
            }
        }
#pragma unroll
        for (int cc = 0; cc < 32; ++cc) {
            int c = c0 + cc;
            hid[r * HS + c] = f2bf(fmaxf(pre[cc] + b1g[c], 0.0f));
        }
    }
    __syncthreads();

    // stage C: L2 MFMA [32 x 256] @ [256 x 512] + bias -> out
    {
        const int m0 = wv * 128;
        f4 acc2[2][8];
#pragma unroll
        for (int rt = 0; rt < 2; ++rt)
#pragma unroll
            for (int c = 0; c < 8; ++c) acc2[rt][c] = (f4){0.f, 0.f, 0.f, 0.f};
        for (int kb = 0; kb < KT2; ++kb) {
            s8 a0 = *(const s8*)&hid[l15 * HS + kb * 32 + quad * 8];
            s8 a1 = *(const s8*)&hid[(l15 + 16) * HS + kb * 32 + quad * 8];
            s8 bfr[8];
#pragma unroll
            for (int c = 0; c < 8; ++c)
                bfr[c] = *(const s8*)&w2p[((size_t)(kb * OUTD + m0 + c * 16 + l15)) * 32 + quad * 8];
#pragma unroll
            for (int c = 0; c < 8; ++c) {
                acc2[0][c] = __builtin_amdgcn_mfma_f32_16x16x32_bf16(a0, bfr[c], acc2[0][c], 0, 0, 0);
                acc2[1][c] = __builtin_amdgcn_mfma_f32_16x16x32_bf16(a1, bfr[c], acc2[1][c], 0, 0, 0);
            }
        }
#pragma unroll
        for (int c = 0; c < 8; ++c) {
            int ccol = m0 + c * 16 + l15;
            float bias = b2g[ccol];
#pragma unroll
            for (int rt = 0; rt < 2; ++rt)
#pragma unroll
                for (int i = 0; i < 4; ++i) {
                    int rr = rt * 16 + quad * 4 + i;
                    out[(size_t)(row0 + rr) * OUTD + ccol] = acc2[rt][c][i] + bias;
                }
        }
    }
}

extern "C" void kernel_launch(void* const* d_in, const int* in_sizes, int n_in,
                              void* d_out, int out_size, void* d_ws, size_t ws_size,
                              hipStream_t stream) {
    (void)in_sizes; (void)n_in; (void)out_size; (void)ws_size;
    const float* src_points   = (const float*)d_in[0];
    const float* tgt_points   = (const float*)d_in[1];
    const float* src_features = (const float*)d_in[2];
    const float* w_sem1 = (const float*)d_in[3];
    const float* b_sem1 = (const float*)d_in[4];
    const float* w_sem2 = (const float*)d_in[5];
    const float* b_sem2 = (const float*)d_in[6];
    const float* w_up1  = (const float*)d_in[7];
    const float* b_up1  = (const float*)d_in[8];
    const float* w_up2  = (const float*)d_in[9];
    const float* b_up2  = (const float*)d_in[10];

    float* out    = (float*)d_out;
    float* ups    = out;
    float* logits = out + (size_t)BB * NN * OUTD;

    // workspace layout (~18.5 MB of 256 MiB)
    char* w = (char*)d_ws;
    unsigned short* T = (unsigned short*)w;    w += (size_t)BB * MM * TS * 2;          // 8388608
    float* pd2  = (float*)w;                   w += (size_t)BB * NN * SPLIT * KNN * 4; // 6291456
    unsigned short* pidx = (unsigned short*)w; w += (size_t)BB * NN * SPLIT * KNN * 2; // 3145728
    unsigned short* w1p  = (unsigned short*)w; w += (size_t)KT1 * H2 * 32 * 2;         // 278528
    unsigned short* w2p  = (unsigned short*)w; w += (size_t)KT2 * OUTD * 32 * 2;       // 262144
    unsigned short* ws1p = (unsigned short*)w; w += (size_t)SKT1 * H1 * 32 * 2;        // 131072
    unsigned short* ws2p = (unsigned short*)w; w += (size_t)SKT2 * 32 * 32 * 2;        // 8192

    prep_kernel<<<dim3(NPREP), dim3(256), 0, stream>>>(
        w_up1, w_up2, w_sem1, w_sem2, w1p, w2p, ws1p, ws2p);
    fused_kernel<<<dim3(NKNNB + NSEMB), dim3(256), 0, stream>>>(
        src_points, tgt_points, pd2, pidx,
        src_features, ws1p, ws2p, w1p, b_sem1, b_sem2, logits, T);
    up_kernel<<<dim3(BB * NN / RR), dim3(256), 0, stream>>>(
        T, pd2, pidx, tgt_points, w2p, b_up1, b_up2, ups);
}

// Round 10
// 154.834 us; speedup vs baseline: 1.0664x; 1.0270x over previous
//
#include <hip/hip_runtime.h>
#include <math.h>

#define BB 2
#define MM 4096
#define NN 8192
#define CC 512
#define NC 20
#define OUTD 512
#define H1 128
#define H2 256
#define CIN 532      // C + NC
#define KNN 3
#define SPLIT 32
#define CHUNK (MM / SPLIT)   // 128
#define CLEN (CHUNK / 4)     // 32 points per chain

// up_kernel MFMA geometry
#define RR 32        // rows per block
#define HS 264       // hidden row stride in bf16
#define KT2 8        // k-tiles layer2 (K=256)
#define KT1 17       // k-tiles of packed W1 (K=544; kb 0..15 feat, kb 16 = P block)

// sem geometry (16 rows per block)
#define RO 16
#define FS 520       // sfeat stride (bf16)
#define HS2 136      // shid stride (bf16)
#define TS 512       // T row: [H(256) | G(256)] bf16
#define SKT1 16      // K=512
#define SKT2 4       // K=128

#define NPREP 544                     // 139264 / 256
#define NKNNB (BB * NN / 256 * SPLIT) // 2048 knn blocks
#define NSEMB (BB * MM / RO)          // 512 sem blocks

typedef __attribute__((ext_vector_type(8))) short s8;
typedef __attribute__((ext_vector_type(4))) float f4;

__device__ inline unsigned short f2bf(float x) {
    unsigned u = __float_as_uint(x);
    unsigned r = (u + 0x7FFFu + ((u >> 16) & 1u)) >> 16;
    return (unsigned short)r;
}
__device__ inline float bf2fs(short u) {
    return __uint_as_float(((unsigned)(unsigned short)u) << 16);
}

// ---------------- K0: pack all bf16 weights ----------------
__global__ __launch_bounds__(256) void prep_kernel(
    const float* __restrict__ wu1, const float* __restrict__ wu2,
    const float* __restrict__ ws1, const float* __restrict__ ws2,
    unsigned short* __restrict__ w1p, unsigned short* __restrict__ w2p,
    unsigned short* __restrict__ ws1p, unsigned short* __restrict__ ws2p)
{
    int i = blockIdx.x * 256 + threadIdx.x;
    if (i < KT1 * H2 * 32) {            // upsample L1 (feat rows 0..511, P rows 512..531)
        int kk = i & 31, n = (i >> 5) & 255, kb = i >> 13;
        int k = kb * 32 + kk;
        w1p[i] = f2bf((k < CIN) ? wu1[(size_t)k * H2 + n] : 0.0f);
    }
    if (i < KT2 * OUTD * 32) {          // upsample L2
        int kk = i & 31, n = (i >> 5) & 511, kb = i >> 14;
        int k = kb * 32 + kk;
        w2p[i] = f2bf(wu2[(size_t)k * OUTD + n]);
    }
    if (i < SKT1 * H1 * 32) {           // semantic L1
        int kk = i & 31, n = (i >> 5) & 127, kb = i >> 12;
        int k = kb * 32 + kk;
        ws1p[i] = f2bf(ws1[(size_t)k * H1 + n]);
    }
    if (i < SKT2 * 32 * 32) {           // semantic L2 (N padded 20->32)
        int kk = i & 31, n = (i >> 5) & 31, kb = i >> 10;
        int k = kb * 32 + kk;
        ws2p[i] = f2bf((n < NC) ? ws2[(size_t)k * NC + n] : 0.0f);
    }
}

// ---------------- K1: fused sem blocks (FIRST) + kNN partial blocks ----------------
// sem blocks dispatched first so their long MFMA/mem work overlaps knn's VALU;
// drain tail is uniform small knn blocks. 23.6 KB LDS -> 6 blocks/CU.
__global__ __launch_bounds__(256) void fused_kernel(
    const float* __restrict__ srcp, const float* __restrict__ tgtp,
    float* __restrict__ pd2, unsigned short* __restrict__ pidx,
    const float* __restrict__ feat,
    const unsigned short* __restrict__ ws1p, const unsigned short* __restrict__ ws2p,
    const unsigned short* __restrict__ w1p,
    const float* __restrict__ b1s, const float* __restrict__ b2s,
    float* __restrict__ logits_out, unsigned short* __restrict__ T)
{
    __shared__ __align__(16) char smem[24128];
    const int tid = threadIdx.x;
    const int bx = blockIdx.x;

    if (bx >= NSEMB) {
        // ================= kNN partial block: one 128-pt chunk vs 256 targets =================
        float4* pts = (float4*)smem;       // 2 KB
        const int idx = bx - NSEMB;        // 0..2047
        const int g = idx & 63;            // target group (uniform)
        const int chunk = idx >> 6;        // 0..31
        const int t = g * 256 + tid;
        const int bu = g >> 5;             // uniform batch
        const int mbase = chunk * CHUNK;

        if (tid < CHUNK) {
            const float* spg = srcp + ((size_t)bu * MM + mbase) * 3;
            float x = spg[tid * 3 + 0];
            float y = spg[tid * 3 + 1];
            float z = spg[tid * 3 + 2];
            pts[tid] = make_float4(x, y, z, x * x + y * y + z * z);
        }
        __syncthreads();

        const float tx = tgtp[(size_t)t * 3 + 0];
        const float ty = tgtp[(size_t)t * 3 + 1];
        const float tz = tgtp[(size_t)t * 3 + 2];
        const float m2x = -2.0f * tx, m2y = -2.0f * ty, m2z = -2.0f * tz;

        float b0[4], b1[4], b2[4];
        int i0[4], i1[4], i2[4];
#pragma unroll
        for (int k = 0; k < 4; ++k) {
            b0[k] = b1[k] = b2[k] = 1e30f;
            i0[k] = i1[k] = i2[k] = 0;
        }

#pragma unroll 4
        for (int m = 0; m < CLEN; ++m) {
#pragma unroll
            for (int k = 0; k < 4; ++k) {
                float4 p = pts[k * CLEN + m];          // broadcast ds_read (conflict-free)
                float d = fmaf(m2x, p.x, fmaf(m2y, p.y, fmaf(m2z, p.z, p.w)));
                int mi = mbase + k * CLEN + m;          // wave-uniform
                bool l2 = d < b2[k], l1 = d < b1[k], l0 = d < b0[k];
                // index sorted-insert (uses OLD indices)
                i2[k] = l1 ? i1[k] : (l2 ? mi : i2[k]);
                i1[k] = l0 ? i0[k] : (l1 ? mi : i1[k]);
                i0[k] = l0 ? mi : i0[k];
                // distance sorted-insert via med3/min (verified == cndmask form, ties incl.)
                b2[k] = __builtin_amdgcn_fmed3f(d, b1[k], b2[k]);
                b1[k] = __builtin_amdgcn_fmed3f(d, b0[k], b1[k]);
                b0[k] = fminf(d, b0[k]);
            }
        }
        // merge chains 1..3 into chain 0 (ascending index ranges -> '<' is stable)
#pragma unroll
        for (int k = 1; k < 4; ++k) {
#pragma unroll
            for (int j = 0; j < 3; ++j) {
                float d = (j == 0) ? b0[k] : (j == 1) ? b1[k] : b2[k];
                int   i = (j == 0) ? i0[k] : (j == 1) ? i1[k] : i2[k];
                bool e2 = d < b2[0], e1 = d < b1[0], e0 = d < b0[0];
                i2[0] = e1 ? i1[0] : (e2 ? i : i2[0]);
                i1[0] = e0 ? i0[0] : (e1 ? i : i1[0]);
                i0[0] = e0 ? i : i0[0];
                b2[0] = __builtin_amdgcn_fmed3f(d, b1[0], b2[0]);
                b1[0] = __builtin_amdgcn_fmed3f(d, b0[0], b1[0]);
                b0[0] = fminf(d, b0[0]);
            }
        }
        size_t o = ((size_t)t * SPLIT + chunk) * KNN;
        pd2[o + 0] = b0[0]; pd2[o + 1] = b1[0]; pd2[o + 2] = b2[0];
        pidx[o + 0] = (unsigned short)i0[0];
        pidx[o + 1] = (unsigned short)i1[0];
        pidx[o + 2] = (unsigned short)i2[0];
        return;
    }

    // ================= semantic / T-table block =================
    unsigned short* sfeat = (unsigned short*)smem;            // 16640 B
    unsigned short* Tst   = (unsigned short*)smem;            // 16384 B (ALIAS of sfeat)
    unsigned short* shid  = (unsigned short*)(smem + 16640);  // 4352 B
    float*          slg   = (float*)(smem + 20992);           // 2112 B [r*33+c]
    unsigned short* pP    = (unsigned short*)(smem + 23104);  // 1024 B
    const int row0 = bx * RO;
    const int lane = tid & 63;
    const int wv = tid >> 6;
    const int l15 = lane & 15;
    const int quad = lane >> 4;

    // stage feat rows as bf16 (16 threads/row)
    {
        const int r = tid >> 4, p = tid & 15;
        const float4* fr = (const float4*)(feat + (size_t)(row0 + r) * CC);
#pragma unroll
        for (int j = 0; j < 8; ++j) {
            int c4 = j * 16 + p;
            float4 a = fr[c4];
            ushort4 s;
            s.x = f2bf(a.x); s.y = f2bf(a.y); s.z = f2bf(a.z); s.w = f2bf(a.w);
            *(ushort4*)&sfeat[r * FS + c4 * 4] = s;
        }
    }
    __syncthreads();

    // combined L1: sem (128 cols) + H (256 cols), K=512
    f4 asem[2], ah[4];
    {
#pragma unroll
        for (int c = 0; c < 2; ++c) asem[c] = (f4){0.f, 0.f, 0.f, 0.f};
#pragma unroll
        for (int c = 0; c < 4; ++c) ah[c] = (f4){0.f, 0.f, 0.f, 0.f};
        for (int kb = 0; kb < SKT1; ++kb) {
            s8 a = *(const s8*)&sfeat[l15 * FS + kb * 32 + quad * 8];
#pragma unroll
            for (int c = 0; c < 2; ++c) {
                s8 b = *(const s8*)&ws1p[((size_t)(kb * H1 + wv * 32 + c * 16 + l15)) * 32 + quad * 8];
                asem[c] = __builtin_amdgcn_mfma_f32_16x16x32_bf16(a, b, asem[c], 0, 0, 0);
            }
#pragma unroll
            for (int c = 0; c < 4; ++c) {
                s8 b = *(const s8*)&w1p[((size_t)(kb * H2 + wv * 64 + c * 16 + l15)) * 32 + quad * 8];
                ah[c] = __builtin_amdgcn_mfma_f32_16x16x32_bf16(a, b, ah[c], 0, 0, 0);
            }
        }
    }
    __syncthreads();   // all sfeat reads complete -> safe to overwrite via Tst alias
    {
#pragma unroll
        for (int c = 0; c < 2; ++c) {
            int col = wv * 32 + c * 16 + l15;
            float bias = b1s[col];
#pragma unroll
            for (int i = 0; i < 4; ++i) {
                int rr = quad * 4 + i;
                shid[rr * HS2 + col] = f2bf(fmaxf(asem[c][i] + bias, 0.0f));
            }
        }
#pragma unroll
        for (int c = 0; c < 4; ++c) {
            int col = wv * 64 + c * 16 + l15;
#pragma unroll
            for (int i = 0; i < 4; ++i) {
                int rr = quad * 4 + i;
                Tst[rr * TS + col] = f2bf(ah[c][i]);   // H (bias added in up_kernel)
            }
        }
    }
    __syncthreads();

    // sem L2: [16 x 128] @ [128 x 32(20)] (waves 0,1)
    if (wv < 2) {
        f4 acc = (f4){0.f, 0.f, 0.f, 0.f};
        for (int kb = 0; kb < SKT2; ++kb) {
            s8 a = *(const s8*)&shid[l15 * HS2 + kb * 32 + quad * 8];
            s8 b = *(const s8*)&ws2p[((size_t)(kb * 32 + wv * 16 + l15)) * 32 + quad * 8];
            acc = __builtin_amdgcn_mfma_f32_16x16x32_bf16(a, b, acc, 0, 0, 0);
        }
        int col = wv * 16 + l15;
        float bias = (col < NC) ? b2s[col] : 0.0f;
#pragma unroll
        for (int i = 0; i < 4; ++i) {
            int rr = quad * 4 + i;
            float v = acc[i] + bias;
            slg[rr * 33 + col] = v;
            if (col < NC)
                logits_out[(size_t)(row0 + rr) * NC + col] = v;
        }
    }
    __syncthreads();

    // softmax -> pP (bf16, padded to 32)
    if (tid < RO) {
        int r = tid;
        float mx = -1e30f;
        for (int nc = 0; nc < NC; ++nc) mx = fmaxf(mx, slg[r * 33 + nc]);
        float s = 0.0f;
        float e[NC];
#pragma unroll
        for (int nc = 0; nc < NC; ++nc) { e[nc] = __expf(slg[r * 33 + nc] - mx); s += e[nc]; }
        float inv = 1.0f / s;
#pragma unroll
        for (int nc = 0; nc < 32; ++nc)
            pP[r * 32 + nc] = (nc < NC) ? f2bf(e[nc] * inv) : 0;
    }
    __syncthreads();

    // G = P @ W1b (K=32, kb=16 of packed W1)
    {
        s8 a = *(const s8*)&pP[l15 * 32 + quad * 8];
#pragma unroll
        for (int c = 0; c < 4; ++c) {
            s8 b = *(const s8*)&w1p[((size_t)(16 * H2 + wv * 64 + c * 16 + l15)) * 32 + quad * 8];
            f4 acc = (f4){0.f, 0.f, 0.f, 0.f};
            acc = __builtin_amdgcn_mfma_f32_16x16x32_bf16(a, b, acc, 0, 0, 0);
            int col = wv * 64 + c * 16 + l15;
#pragma unroll
            for (int i = 0; i < 4; ++i) {
                int rr = quad * 4 + i;
                Tst[rr * TS + 256 + col] = f2bf(acc[i]);
            }
        }
    }
    __syncthreads();

    // coalesced store of T rows
    {
#pragma unroll
        for (int v = 0; v < 4; ++v) {
            int e = (tid + v * 256) * 8;            // 0..8191, step 8
            int r = e >> 9, c = e & (TS - 1);
            s8 d = *(const s8*)&Tst[e];
            *(s8*)&T[((size_t)(row0 + r)) * TS + c] = d;
        }
    }
}

// ---------------- K2: merge + T-gather + L2 MFMA ----------------
__global__ __launch_bounds__(256) void up_kernel(
    const unsigned short* __restrict__ T,
    const float* __restrict__ pd2, const unsigned short* __restrict__ pidx,
    const float* __restrict__ tgtp,
    const unsigned short* __restrict__ w2p,
    const float* __restrict__ b1g, const float* __restrict__ b2g,
    float* __restrict__ out)
{
    __shared__ unsigned short hid[RR * HS];
    __shared__ float sg[RR][3];
    __shared__ int   sj[RR][3];
    __shared__ float pb[RR][4][3];
    __shared__ int   pi[RR][4][3];
    const int tid = threadIdx.x;
    const int row0 = blockIdx.x * RR;
    const int lane = tid & 63;
    const int wv = tid >> 6;
    const int l15 = lane & 15;
    const int quad = lane >> 4;

    // stage A1: 4 threads/row, each merges 8 chunks (24 partial entries)
    if (tid < RR * 4) {
        const int r = tid >> 2, p = tid & 3;
        int row = row0 + r;
        float b0 = 1e30f, b1 = 1e30f, b2 = 1e30f;
        int i0 = 0, i1 = 0, i2 = 0;
        size_t base = (size_t)row * SPLIT * KNN + (size_t)p * 8 * KNN;
#pragma unroll
        for (int j = 0; j < 8 * KNN; ++j) {
            float d = pd2[base + j];
            int m = pidx[base + j];
            bool l2 = d < b2, l1 = d < b1, l0 = d < b0;
            i2 = l1 ? i1 : (l2 ? m : i2);
            i1 = l0 ? i0 : (l1 ? m : i1);
            i0 = l0 ? m : i0;
            b2 = __builtin_amdgcn_fmed3f(d, b1, b2);
            b1 = __builtin_amdgcn_fmed3f(d, b0, b1);
            b0 = fminf(d, b0);
        }
        pb[r][p][0] = b0; pb[r][p][1] = b1; pb[r][p][2] = b2;
        pi[r][p][0] = i0; pi[r][p][1] = i1; pi[r][p][2] = i2;
    }
    __syncthreads();

    // stage A2: final merge of 12 entries + softmax(-d) weights
    if (tid < RR) {
        int row = row0 + tid;
        float b0 = 1e30f, b1 = 1e30f, b2 = 1e30f;
        int i0 = 0, i1 = 0, i2 = 0;
#pragma unroll
        for (int p = 0; p < 4; ++p)
#pragma unroll
            for (int j = 0; j < 3; ++j) {
                float d = pb[tid][p][j];
                int m = pi[tid][p][j];
                bool l2 = d < b2, l1 = d < b1, l0 = d < b0;
                i2 = l1 ? i1 : (l2 ? m : i2);
                i1 = l0 ? i0 : (l1 ? m : i1);
                i0 = l0 ? m : i0;
                b2 = __builtin_amdgcn_fmed3f(d, b1, b2);
                b1 = __builtin_amdgcn_fmed3f(d, b0, b1);
                b0 = fminf(d, b0);
            }
        float tx = tgtp[(size_t)row * 3 + 0];
        float ty = tgtp[(size_t)row * 3 + 1];
        float tz = tgtp[(size_t)row * 3 + 2];
        float t2 = tx * tx + ty * ty + tz * tz;
        float d0 = sqrtf(fmaxf(b0 + t2, 0.0f));
        float d1 = sqrtf(fmaxf(b1 + t2, 0.0f));
        float d2v = sqrtf(fmaxf(b2 + t2, 0.0f));
        float e1 = __expf(d0 - d1);
        float e2 = __expf(d0 - d2v);
        float inv = 1.0f / (1.0f + e1 + e2);
        sg[tid][0] = inv; sg[tid][1] = e1 * inv; sg[tid][2] = e2 * inv;
        sj[tid][0] = i0; sj[tid][1] = i1; sj[tid][2] = i2;
    }
    __syncthreads();

    // stage B: gather T rows, pre = sum g_k*H[j_k] + (1/3) sum G[j_k]; relu -> hid
    {
        const int r = tid >> 3, p = tid & 7, c0 = p * 32;
        int row = row0 + r;
        size_t bofs = (size_t)(row >> 13) * MM;
        float pre[32];
#pragma unroll
        for (int cc = 0; cc < 32; ++cc) pre[cc] = 0.0f;
#pragma unroll
        for (int k = 0; k < 3; ++k) {
            const unsigned short* Tr = T + (bofs + (size_t)sj[r][k]) * TS;
            float gk = sg[r][k];
#pragma unroll
            for (int v = 0; v < 4; ++v) {
                s8 h = *(const s8*)&Tr[c0 + v * 8];
                s8 g = *(const s8*)&Tr[256 + c0 + v * 8];
#pragma unroll
                for (int e = 0; e < 8; ++e) {
                    pre[v * 8 + e] = fmaf(gk, bf2fs(h[e]), pre[v * 8 + e]);
                    pre[v * 8 + e] = fmaf(1.0f / 3.0f, bf2fs(g[e]), pre[v * 8 + e]);
                }
            }
        }
#pragma unroll
        for (int cc = 0; cc < 32; ++cc) {
            int c = c0 + cc;
            hid[r * HS + c] = f2bf(fmaxf(pre[cc] + b1g[c], 0.0f));
        }
    }
    __syncthreads();

    // stage C: L2 MFMA [32 x 256] @ [256 x 512] + bias -> out
    {
        const int m0 = wv * 128;
        f4 acc2[2][8];
#pragma unroll
        for (int rt = 0; rt < 2; ++rt)
#pragma unroll
            for (int c = 0; c < 8; ++c) acc2[rt][c] = (f4){0.f, 0.f, 0.f, 0.f};
        for (int kb = 0; kb < KT2; ++kb) {
            s8 a0 = *(const s8*)&hid[l15 * HS + kb * 32 + quad * 8];
            s8 a1 = *(const s8*)&hid[(l15 + 16) * HS + kb * 32 + quad * 8];
            s8 bfr[8];
#pragma unroll
            for (int c = 0; c < 8; ++c)
                bfr[c] = *(const s8*)&w2p[((size_t)(kb * OUTD + m0 + c * 16 + l15)) * 32 + quad * 8];
#pragma unroll
            for (int c = 0; c < 8; ++c) {
                acc2[0][c] = __builtin_amdgcn_mfma_f32_16x16x32_bf16(a0, bfr[c], acc2[0][c], 0, 0, 0);
                acc2[1][c] = __builtin_amdgcn_mfma_f32_16x16x32_bf16(a1, bfr[c], acc2[1][c], 0, 0, 0);
            }
        }
#pragma unroll
        for (int c = 0; c < 8; ++c) {
            int ccol = m0 + c * 16 + l15;
            float bias = b2g[ccol];
#pragma unroll
            for (int rt = 0; rt < 2; ++rt)
#pragma unroll
                for (int i = 0; i < 4; ++i) {
                    int rr = rt * 16 + quad * 4 + i;
                    out[(size_t)(row0 + rr) * OUTD + ccol] = acc2[rt][c][i] + bias;
                }
        }
    }
}

extern "C" void kernel_launch(void* const* d_in, const int* in_sizes, int n_in,
                              void* d_out, int out_size, void* d_ws, size_t ws_size,
                              hipStream_t stream) {
    (void)in_sizes; (void)n_in; (void)out_size; (void)ws_size;
    const float* src_points   = (const float*)d_in[0];
    const float* tgt_points   = (const float*)d_in[1];
    const float* src_features = (const float*)d_in[2];
    const float* w_sem1 = (const float*)d_in[3];
    const float* b_sem1 = (const float*)d_in[4];
    const float* w_sem2 = (const float*)d_in[5];
    const float* b_sem2 = (const float*)d_in[6];
    const float* w_up1  = (const float*)d_in[7];
    const float* b_up1  = (const float*)d_in[8];
    const float* w_up2  = (const float*)d_in[9];
    const float* b_up2  = (const float*)d_in[10];

    float* out    = (float*)d_out;
    float* ups    = out;
    float* logits = out + (size_t)BB * NN * OUTD;

    // workspace layout (~18.5 MB of 256 MiB)
    char* w = (char*)d_ws;
    unsigned short* T = (unsigned short*)w;    w += (size_t)BB * MM * TS * 2;          // 8388608
    float* pd2  = (float*)w;                   w += (size_t)BB * NN * SPLIT * KNN * 4; // 6291456
    unsigned short* pidx = (unsigned short*)w; w += (size_t)BB * NN * SPLIT * KNN * 2; // 3145728
    unsigned short* w1p  = (unsigned short*)w; w += (size_t)KT1 * H2 * 32 * 2;         // 278528
    unsigned short* w2p  = (unsigned short*)w; w += (size_t)KT2 * OUTD * 32 * 2;       // 262144
    unsigned short* ws1p = (unsigned short*)w; w += (size_t)SKT1 * H1 * 32 * 2;        // 131072
    unsigned short* ws2p = (unsigned short*)w; w += (size_t)SKT2 * 32 * 32 * 2;        // 8192

    prep_kernel<<<dim3(NPREP), dim3(256), 0, stream>>>(
        w_up1, w_up2, w_sem1, w_sem2, w1p, w2p, ws1p, ws2p);
    fused_kernel<<<dim3(NSEMB + NKNNB), dim3(256), 0, stream>>>(
        src_points, tgt_points, pd2, pidx,
        src_features, ws1p, ws2p, w1p, b_sem1, b_sem2, logits, T);
    up_kernel<<<dim3(BB * NN / RR), dim3(256), 0, stream>>>(
        T, pd2, pidx, tgt_points, w2p, b_up1, b_up2, ups);
}